// Round 1
// baseline (93.763 us; speedup 1.0000x reference)
//
#include <hip/hip_runtime.h>
#include <math.h>

#define NN 2048
#define DD 64
#define HH 64
#define TI 128
#define TJ 64

// ---------------------------------------------------------------------------
// Stage 1: u[i][h] = dot(z[i,:], W1[h,0:64])  + b1[h]
//          v[i][h] = dot(z[i,:], W1[h,64:128])
// Row-major outputs, coalesced writes. ~33 MFLOP total -> noise.
// ---------------------------------------------------------------------------
__global__ __launch_bounds__(256) void prep_kernel(
    const float* __restrict__ z, const float* __restrict__ W1,
    const float* __restrict__ b1, float* __restrict__ u, float* __restrict__ v) {
  __shared__ float zs[8 * DD];
  const int t = threadIdx.x;
  const int i0 = blockIdx.x * 8;
  if (t < 128) {
    reinterpret_cast<float4*>(zs)[t] =
        reinterpret_cast<const float4*>(z + (size_t)i0 * DD)[t];
  }
  __syncthreads();

  const int hs = t & 127;   // 0..127: h + side
  const int rg = t >> 7;    // 0..1: which 4-row group
  const int h = hs & 63;
  const int side = hs >> 6; // 0 -> u (Wa), 1 -> v (Wb)
  const float* wrow = W1 + h * (2 * DD) + side * DD;

  float acc0 = 0.f, acc1 = 0.f, acc2 = 0.f, acc3 = 0.f;
#pragma unroll
  for (int d4 = 0; d4 < DD / 4; ++d4) {
    const float4 wv = reinterpret_cast<const float4*>(wrow)[d4];
    const float* z0 = zs + (rg * 4 + 0) * DD + d4 * 4;
    const float* z1 = z0 + DD;
    const float* z2 = z1 + DD;
    const float* z3 = z2 + DD;
    acc0 = fmaf(z0[3], wv.w, fmaf(z0[2], wv.z, fmaf(z0[1], wv.y, fmaf(z0[0], wv.x, acc0))));
    acc1 = fmaf(z1[3], wv.w, fmaf(z1[2], wv.z, fmaf(z1[1], wv.y, fmaf(z1[0], wv.x, acc1))));
    acc2 = fmaf(z2[3], wv.w, fmaf(z2[2], wv.z, fmaf(z2[1], wv.y, fmaf(z2[0], wv.x, acc2))));
    acc3 = fmaf(z3[3], wv.w, fmaf(z3[2], wv.z, fmaf(z3[1], wv.y, fmaf(z3[0], wv.x, acc3))));
  }
  const float bias = side ? 0.0f : b1[h];
  float* dst = side ? v : u;
  const int ib = i0 + rg * 4;
  dst[(size_t)(ib + 0) * HH + h] = acc0 + bias;
  dst[(size_t)(ib + 1) * HH + h] = acc1 + bias;
  dst[(size_t)(ib + 2) * HH + h] = acc2 + bias;
  dst[(size_t)(ib + 3) * HH + h] = acc3 + bias;
}

// ---------------------------------------------------------------------------
// Stage 2: out[i][j] = sigmoid( sum_h relu(u[i][h]+v[j][h]) * W2[h] + b2 ),
// diagonal zeroed. 128x64 tile per block, 256 threads, 8x4 micro-tile.
// LDS tiles stored transposed [h][i] via in-register 4x4 transpose staging.
// ---------------------------------------------------------------------------
__global__ __launch_bounds__(256) void pair_kernel(
    const float* __restrict__ u, const float* __restrict__ v,
    const float* __restrict__ W2, const float* __restrict__ b2,
    float* __restrict__ out) {
  __shared__ float su[HH * TI];  // [h][i-local], 32 KB
  __shared__ float sv[HH * TJ];  // [h][j-local], 16 KB

  const int t = threadIdx.x;
  const int i0 = blockIdx.y * TI;
  const int j0 = blockIdx.x * TJ;

  // ---- staging with in-register transpose (all b128, ~2-way conflicts max)
  const int c4 = t & 15;        // h-quad: h = c4*4 + q
  const int rq = (t >> 4) * 4;  // row start within a 64-row group
#pragma unroll
  for (int k = 0; k < 2; ++k) {  // u: 128 rows
    const int row = rq + k * 64;
    const float* src = u + (size_t)(i0 + row) * HH + c4 * 4;
    const float4 a0 = *reinterpret_cast<const float4*>(src);
    const float4 a1 = *reinterpret_cast<const float4*>(src + HH);
    const float4 a2 = *reinterpret_cast<const float4*>(src + 2 * HH);
    const float4 a3 = *reinterpret_cast<const float4*>(src + 3 * HH);
    *reinterpret_cast<float4*>(&su[(c4 * 4 + 0) * TI + row]) = make_float4(a0.x, a1.x, a2.x, a3.x);
    *reinterpret_cast<float4*>(&su[(c4 * 4 + 1) * TI + row]) = make_float4(a0.y, a1.y, a2.y, a3.y);
    *reinterpret_cast<float4*>(&su[(c4 * 4 + 2) * TI + row]) = make_float4(a0.z, a1.z, a2.z, a3.z);
    *reinterpret_cast<float4*>(&su[(c4 * 4 + 3) * TI + row]) = make_float4(a0.w, a1.w, a2.w, a3.w);
  }
  {  // v: 64 rows
    const float* src = v + (size_t)(j0 + rq) * HH + c4 * 4;
    const float4 a0 = *reinterpret_cast<const float4*>(src);
    const float4 a1 = *reinterpret_cast<const float4*>(src + HH);
    const float4 a2 = *reinterpret_cast<const float4*>(src + 2 * HH);
    const float4 a3 = *reinterpret_cast<const float4*>(src + 3 * HH);
    *reinterpret_cast<float4*>(&sv[(c4 * 4 + 0) * TJ + rq]) = make_float4(a0.x, a1.x, a2.x, a3.x);
    *reinterpret_cast<float4*>(&sv[(c4 * 4 + 1) * TJ + rq]) = make_float4(a0.y, a1.y, a2.y, a3.y);
    *reinterpret_cast<float4*>(&sv[(c4 * 4 + 2) * TJ + rq]) = make_float4(a0.z, a1.z, a2.z, a3.z);
    *reinterpret_cast<float4*>(&sv[(c4 * 4 + 3) * TJ + rq]) = make_float4(a0.w, a1.w, a2.w, a3.w);
  }
  __syncthreads();

  const int tx = t & 15;  // j-group: j = j0 + tx*4 + b
  const int ty = t >> 4;  // i-group: i = i0 + ty*8 + a

  float acc[8][4] = {};
#pragma unroll 4
  for (int h = 0; h < HH; ++h) {
    const float wh = W2[h];  // uniform -> s_load, scalar pipe
    const float4 uaL = *reinterpret_cast<const float4*>(&su[h * TI + ty * 8]);
    const float4 uaH = *reinterpret_cast<const float4*>(&su[h * TI + ty * 8 + 4]);
    const float4 vbv = *reinterpret_cast<const float4*>(&sv[h * TJ + tx * 4]);
    const float ua[8] = {uaL.x, uaL.y, uaL.z, uaL.w, uaH.x, uaH.y, uaH.z, uaH.w};
    const float vb[4] = {vbv.x, vbv.y, vbv.z, vbv.w};
#pragma unroll
    for (int a = 0; a < 8; ++a) {
#pragma unroll
      for (int b = 0; b < 4; ++b) {
        float s = ua[a] + vb[b];
        s = fmaxf(s, 0.0f);
        acc[a][b] = fmaf(s, wh, acc[a][b]);
      }
    }
  }

  const float bb = b2[0];
#pragma unroll
  for (int a = 0; a < 8; ++a) {
    const int i = i0 + ty * 8 + a;
    float4 r;
    {
      const float x0 = acc[a][0] + bb;
      const float x1 = acc[a][1] + bb;
      const float x2 = acc[a][2] + bb;
      const float x3 = acc[a][3] + bb;
      r.x = 1.0f / (1.0f + __expf(-x0));
      r.y = 1.0f / (1.0f + __expf(-x1));
      r.z = 1.0f / (1.0f + __expf(-x2));
      r.w = 1.0f / (1.0f + __expf(-x3));
    }
    const int jb = j0 + tx * 4;
    if (i - jb >= 0 && i - jb < 4) {  // zero the diagonal element if inside
      if (i - jb == 0) r.x = 0.0f;
      else if (i - jb == 1) r.y = 0.0f;
      else if (i - jb == 2) r.z = 0.0f;
      else r.w = 0.0f;
    }
    *reinterpret_cast<float4*>(out + (size_t)i * NN + jb) = r;
  }
}

extern "C" void kernel_launch(void* const* d_in, const int* in_sizes, int n_in,
                              void* d_out, int out_size, void* d_ws, size_t ws_size,
                              hipStream_t stream) {
  const float* z  = (const float*)d_in[0];
  const float* W1 = (const float*)d_in[1];
  const float* b1 = (const float*)d_in[2];
  const float* W2 = (const float*)d_in[3];
  const float* b2 = (const float*)d_in[4];
  float* out = (float*)d_out;

  float* u = (float*)d_ws;              // 2048*64 f32 = 512 KB
  float* v = u + (size_t)NN * HH;       // 512 KB more

  prep_kernel<<<NN / 8, 256, 0, stream>>>(z, W1, b1, u, v);
  pair_kernel<<<dim3(NN / TJ, NN / TI), 256, 0, stream>>>(u, v, W2, b2, out);
}